// Round 1
// baseline (2884.294 us; speedup 1.0000x reference)
//
#include <hip/hip_runtime.h>

#define BATCH 65536
#define VEC 512
#define K 1024
#define GAMMA 0.99f
#define EPS 1e-05f

// ---------------- ws layout (all 4-byte elems) ----------------
// w2      : K floats
// cs      : K floats
// counts  : K ints
// cursor  : K ints
// offsets : K ints
// argmin  : BATCH ints
// sorted  : BATCH ints
// total = 5*K + 2*BATCH elems = 544,768 bytes

// ---- kernel 0: column norms of weight (VEC,K) ----
__global__ void k_w2(const float* __restrict__ w, float* __restrict__ w2) {
    int c = blockIdx.x * blockDim.x + threadIdx.x;   // 0..K-1
    float s = 0.f;
    for (int v = 0; v < VEC; ++v) {
        float t = w[v * K + c];
        s += t * t;
    }
    w2[c] = s;
}

// ---- kernel 1: fused distance GEMM + per-row argmin + histogram ----
// block: 256 threads, 32 rows x 1024 cols. wave w handles rows [w*8, w*8+8),
// lane handles cols {chunk*128 + lane, chunk*128 + lane + 64}.
__launch_bounds__(256, 2)
__global__ void k_argmin(const float* __restrict__ x, const float* __restrict__ w,
                         const float* __restrict__ w2, int* __restrict__ am,
                         int* __restrict__ counts) {
    __shared__ float xs[32 * VEC];   // 64 KB
    const int tid = threadIdx.x;
    const long row0 = (long)blockIdx.x * 32;

    const float4* xv = (const float4*)(x + (size_t)row0 * VEC);
    float4* xsv = (float4*)xs;
#pragma unroll
    for (int i = 0; i < 16; ++i) xsv[tid + i * 256] = xv[tid + i * 256];
    __syncthreads();

    const int wgrp = tid >> 6;     // row group 0..3
    const int lane = tid & 63;
    const float* xrow = xs + (wgrp * 8) * VEC;

    float bestv[8];
    int   besti[8];
#pragma unroll
    for (int r = 0; r < 8; ++r) { bestv[r] = 3.4e38f; besti[r] = 0; }

    for (int chunk = 0; chunk < 8; ++chunk) {
        const int c0 = chunk * 128 + lane;   // second col is c0+64
        float acc0[8], acc1[8];
#pragma unroll
        for (int r = 0; r < 8; ++r) { acc0[r] = 0.f; acc1[r] = 0.f; }

        const float* wp = w + c0;
        for (int v = 0; v < VEC; v += 4) {
            const float* wv = wp + (size_t)v * K;
            float w00 = wv[0],       w01 = wv[64];
            float w10 = wv[K],       w11 = wv[K + 64];
            float w20 = wv[2 * K],   w21 = wv[2 * K + 64];
            float w30 = wv[3 * K],   w31 = wv[3 * K + 64];
#pragma unroll
            for (int r = 0; r < 8; ++r) {
                const float4 xr = *(const float4*)(xrow + r * VEC + v);
                acc0[r] += xr.x * w00 + xr.y * w10 + xr.z * w20 + xr.w * w30;
                acc1[r] += xr.x * w01 + xr.y * w11 + xr.z * w21 + xr.w * w31;
            }
        }
        float w2a = w2[c0], w2b = w2[c0 + 64];
#pragma unroll
        for (int r = 0; r < 8; ++r) {
            float d0 = w2a - 2.f * acc0[r];
            float d1 = w2b - 2.f * acc1[r];
            if (d0 < bestv[r]) { bestv[r] = d0; besti[r] = c0; }
            if (d1 < bestv[r]) { bestv[r] = d1; besti[r] = c0 + 64; }
        }
    }

    // cross-lane argmin per row (64 lanes), tie-break to lower index
#pragma unroll
    for (int r = 0; r < 8; ++r) {
        float v = bestv[r];
        int   i = besti[r];
        for (int s = 32; s > 0; s >>= 1) {
            float ov = __shfl_xor(v, s);
            int   oi = __shfl_xor(i, s);
            if (ov < v || (ov == v && oi < i)) { v = ov; i = oi; }
        }
        if (lane == 0) {
            int row = (int)row0 + wgrp * 8 + r;
            am[row] = i;
            atomicAdd(&counts[i], 1);
        }
    }
}

// ---- kernel 2: scan of counts -> offsets; EMA cluster sizes -> cs ----
__global__ void k_scan(const int* __restrict__ counts,
                       const float* __restrict__ cluster_size,
                       int* __restrict__ offsets, float* __restrict__ cs) {
    __shared__ int sa[K];
    __shared__ int sb[K];
    __shared__ float sf[K];
    const int t = threadIdx.x;   // 0..K-1 (1024 threads)
    const int c = counts[t];

    sa[t] = c;
    __syncthreads();
    int* src = sa;
    int* dst = sb;
    for (int d = 1; d < K; d <<= 1) {
        dst[t] = src[t] + ((t >= d) ? src[t - d] : 0);
        __syncthreads();
        int* tmp = src; src = dst; dst = tmp;
    }
    offsets[t] = src[t] - c;   // exclusive scan

    float ncs = GAMMA * cluster_size[t] + (1.0f - GAMMA) * ((c == 0) ? 1.0f : (float)c);
    sf[t] = ncs;
    __syncthreads();
    for (int d = K / 2; d > 0; d >>= 1) {
        if (t < d) sf[t] += sf[t + d];
        __syncthreads();
    }
    float n = sf[0];
    cs[t] = (ncs + EPS) / (n + (float)K * EPS) * n;
}

// ---- kernel 3: counting-sort scatter ----
__global__ void k_scatter(const int* __restrict__ am, const int* __restrict__ offsets,
                          int* __restrict__ cursor, int* __restrict__ sorted) {
    int b = blockIdx.x * blockDim.x + threadIdx.x;
    int k = am[b];
    int pos = atomicAdd(&cursor[k], 1);
    sorted[offsets[k] + pos] = b;
}

// ---- kernel 4: per-cluster gather-sum + EMA + normalize -> out ----
__launch_bounds__(512)
__global__ void k_final(const float* __restrict__ x, const int* __restrict__ sorted,
                        const int* __restrict__ offsets, const int* __restrict__ counts,
                        const float* __restrict__ embed_avg, const float* __restrict__ cs,
                        float* __restrict__ out) {
    __shared__ int idx[2048];
    const int k = blockIdx.x;
    const int t = threadIdx.x;   // 0..511 == v
    const int off = offsets[k];
    const int cnt = counts[k];

    float a0 = 0.f, a1 = 0.f, a2 = 0.f, a3 = 0.f;
    for (int base = 0; base < cnt; base += 2048) {
        int m = min(2048, cnt - base);
        for (int i = t; i < m; i += 512) idx[i] = sorted[off + base + i];
        __syncthreads();
        int i = 0;
        for (; i + 4 <= m; i += 4) {
            long i0 = idx[i + 0], i1 = idx[i + 1], i2 = idx[i + 2], i3 = idx[i + 3];
            a0 += x[i0 * VEC + t];
            a1 += x[i1 * VEC + t];
            a2 += x[i2 * VEC + t];
            a3 += x[i3 * VEC + t];
        }
        for (; i < m; ++i) {
            long i0 = idx[i];
            a0 += x[i0 * VEC + t];
        }
        __syncthreads();
    }
    float es = (a0 + a1) + (a2 + a3);
    float val = (GAMMA * embed_avg[(size_t)t * K + k] + (1.0f - GAMMA) * es) / cs[k];
    out[(size_t)t * K + k] = val;
}

extern "C" void kernel_launch(void* const* d_in, const int* in_sizes, int n_in,
                              void* d_out, int out_size, void* d_ws, size_t ws_size,
                              hipStream_t stream) {
    const float* x            = (const float*)d_in[0];   // (BATCH, VEC)
    const float* w            = (const float*)d_in[1];   // (VEC, K)
    const float* cluster_size = (const float*)d_in[2];   // (K,)
    const float* embed_avg    = (const float*)d_in[3];   // (VEC, K)
    float* out = (float*)d_out;                          // (VEC, K)

    float* w2      = (float*)d_ws;
    float* cs      = w2 + K;
    int*   counts  = (int*)(cs + K);
    int*   cursor  = counts + K;
    int*   offsets = cursor + K;
    int*   am      = offsets + K;
    int*   sorted  = am + BATCH;

    // zero counts + cursor (adjacent)
    hipMemsetAsync(counts, 0, 2 * K * sizeof(int), stream);

    k_w2<<<K / 256, 256, 0, stream>>>(w, w2);
    k_argmin<<<BATCH / 32, 256, 0, stream>>>(x, w, w2, am, counts);
    k_scan<<<1, K, 0, stream>>>(counts, cluster_size, offsets, cs);
    k_scatter<<<BATCH / 256, 256, 0, stream>>>(am, offsets, cursor, sorted);
    k_final<<<K, 512, 0, stream>>>(x, sorted, offsets, counts, embed_avg, cs, out);
}

// Round 2
// 1217.897 us; speedup vs baseline: 2.3683x; 2.3683x over previous
//
#include <hip/hip_runtime.h>

typedef unsigned int uint;
typedef unsigned short ushort_t;
typedef unsigned long long u64;
typedef __attribute__((ext_vector_type(4))) float f32x4;
typedef __attribute__((ext_vector_type(8))) __bf16 bf16x8;
typedef __attribute__((ext_vector_type(8))) unsigned short us8;

#define BATCH 65536
#define VEC 512
#define K 1024
#define GAMMA 0.99f
#define EPS 1e-05f

#define BM 128
#define BN 128
#define BK 32
#define NK (VEC / BK)   // 16

// split f32 -> bf16 hi + bf16 lo (truncation; |err| <= 2^-16 |f|)
__device__ __forceinline__ void cvt_hilo(float f, ushort_t& hi, ushort_t& lo) {
    uint b = __float_as_uint(f);
    hi = (ushort_t)(b >> 16);
    float fhi = __uint_as_float(b & 0xffff0000u);
    float flo = f - fhi;                       // exact
    lo = (ushort_t)(__float_as_uint(flo) >> 16);
}

// ---- kernel: column norms of weight (VEC,K), deterministic ----
// grid 64 blocks x 256 thr; block b covers cols [b*16, b*16+16)
__global__ void k_w2(const float* __restrict__ w, float* __restrict__ w2) {
    __shared__ float red[16][17];
    const int c = blockIdx.x * 16 + (threadIdx.x & 15);
    const int vg = threadIdx.x >> 4;           // 0..15, 32 v each
    float s = 0.f;
    for (int i = 0; i < 32; ++i) {
        float t = w[(size_t)(vg * 32 + i) * K + c];
        s += t * t;
    }
    red[vg][threadIdx.x & 15] = s;
    __syncthreads();
    if (vg == 0) {
        float acc = 0.f;
#pragma unroll
        for (int g = 0; g < 16; ++g) acc += red[g][threadIdx.x & 15];
        w2[c] = acc;
    }
}

// ---- main kernel: split-bf16 MFMA distance GEMM + per-row argmin merge ----
// grid = (BATCH/BM) * (K/BN) = 512*8 = 4096 blocks of 256 threads.
// LDS fragment layout: [slab/ct][half(hi,lo)][lane][8 bf16], lane=(rc&15)|(k8<<4)
__launch_bounds__(256, 2)
__global__ void k_gemm_argmin(const float* __restrict__ x, const float* __restrict__ w,
                              const float* __restrict__ w2, u64* __restrict__ keys) {
    __shared__ ushort_t a_lds[2][8][2][64][8];   // 32 KB
    __shared__ ushort_t b_lds[2][8][2][64][8];   // 32 KB

    const int blk = blockIdx.x;
    const int gx = blk & 7;                  // col block (fast -> row-slab L2 reuse)
    const int gy = blk >> 3;
    const int row0 = gy * BM;
    const int col0 = gx * BN;
    const int t = threadIdx.x;

    // staging identities
    const int a_row = t >> 1;                // 0..127
    const int a_j8 = (t & 1) * 2;            // chunk pair {a_j8, a_j8+1}
    const int b_col = t & 127;
    const int b_j8 = t >> 7;                 // chunk pair {b_j8, b_j8+2}

    float4 aR[4];
    float  bR[16];

    auto stage_load = [&](int ks) {
        const float* ap = x + (size_t)(row0 + a_row) * VEC + ks * BK + a_j8 * 8;
        aR[0] = *(const float4*)(ap + 0);
        aR[1] = *(const float4*)(ap + 4);
        aR[2] = *(const float4*)(ap + 8);
        aR[3] = *(const float4*)(ap + 12);
        const float* bp = w + (size_t)(ks * BK + b_j8 * 8) * K + col0 + b_col;
#pragma unroll
        for (int j = 0; j < 8; ++j) bR[j] = bp[(size_t)j * K];
        const float* bp2 = bp + (size_t)16 * K;
#pragma unroll
        for (int j = 0; j < 8; ++j) bR[8 + j] = bp2[(size_t)j * K];
    };

    auto stage_write = [&](int buf) {
        const float* af = (const float*)aR;
        const int slab = a_row >> 4;
#pragma unroll
        for (int c = 0; c < 2; ++c) {
            us8 hi, lo;
#pragma unroll
            for (int j = 0; j < 8; ++j) {
                ushort_t h, l; cvt_hilo(af[c * 8 + j], h, l);
                hi[j] = h; lo[j] = l;
            }
            const int lane = (a_row & 15) | ((a_j8 + c) << 4);
            *(us8*)&a_lds[buf][slab][0][lane][0] = hi;
            *(us8*)&a_lds[buf][slab][1][lane][0] = lo;
        }
        const int ct = b_col >> 4;
#pragma unroll
        for (int c = 0; c < 2; ++c) {
            us8 hi, lo;
#pragma unroll
            for (int j = 0; j < 8; ++j) {
                ushort_t h, l; cvt_hilo(bR[c * 8 + j], h, l);
                hi[j] = h; lo[j] = l;
            }
            const int lane = (b_col & 15) | ((b_j8 + 2 * c) << 4);
            *(us8*)&b_lds[buf][ct][0][lane][0] = hi;
            *(us8*)&b_lds[buf][ct][1][lane][0] = lo;
        }
    };

    const int wv = t >> 6;
    const int lane = t & 63;
    const int wr = wv >> 1;                  // row half (64 rows)
    const int wc = wv & 1;                   // col half (64 cols)

    f32x4 acc[4][4];
#pragma unroll
    for (int i = 0; i < 4; ++i)
#pragma unroll
        for (int j = 0; j < 4; ++j) acc[i][j] = (f32x4){0.f, 0.f, 0.f, 0.f};

    stage_load(0);
    stage_write(0);
    __syncthreads();

    for (int ks = 0; ks < NK; ++ks) {
        const int buf = ks & 1;
        if (ks + 1 < NK) stage_load(ks + 1);

        bf16x8 ah[4], al[4];
#pragma unroll
        for (int rt = 0; rt < 4; ++rt) {
            ah[rt] = __builtin_bit_cast(bf16x8, *(const us8*)&a_lds[buf][wr * 4 + rt][0][lane][0]);
            al[rt] = __builtin_bit_cast(bf16x8, *(const us8*)&a_lds[buf][wr * 4 + rt][1][lane][0]);
        }
#pragma unroll
        for (int ct = 0; ct < 4; ++ct) {
            bf16x8 bh = __builtin_bit_cast(bf16x8, *(const us8*)&b_lds[buf][wc * 4 + ct][0][lane][0]);
            bf16x8 bl = __builtin_bit_cast(bf16x8, *(const us8*)&b_lds[buf][wc * 4 + ct][1][lane][0]);
#pragma unroll
            for (int rt = 0; rt < 4; ++rt) {
                acc[rt][ct] = __builtin_amdgcn_mfma_f32_16x16x32_bf16(ah[rt], bh, acc[rt][ct], 0, 0, 0);
                acc[rt][ct] = __builtin_amdgcn_mfma_f32_16x16x32_bf16(ah[rt], bl, acc[rt][ct], 0, 0, 0);
                acc[rt][ct] = __builtin_amdgcn_mfma_f32_16x16x32_bf16(al[rt], bh, acc[rt][ct], 0, 0, 0);
            }
        }
        if (ks + 1 < NK) stage_write(buf ^ 1);
        __syncthreads();
    }

    // epilogue: dist = w2 - 2*dot, per-row argmin over the wave's 64 cols,
    // merge across blocks with atomicMin on (sortable_dist<<32 | col)
    float w2c[4];
#pragma unroll
    for (int ct = 0; ct < 4; ++ct)
        w2c[ct] = w2[col0 + wc * 64 + ct * 16 + (lane & 15)];

#pragma unroll
    for (int rt = 0; rt < 4; ++rt) {
#pragma unroll
        for (int reg = 0; reg < 4; ++reg) {
            u64 km = ~0ull;
#pragma unroll
            for (int ct = 0; ct < 4; ++ct) {
                float dist = w2c[ct] - 2.0f * acc[rt][ct][reg];
                uint su = __float_as_uint(dist);
                su = (su & 0x80000000u) ? ~su : (su | 0x80000000u);
                const int col = col0 + wc * 64 + ct * 16 + (lane & 15);
                u64 key = ((u64)su << 32) | (uint)col;
                km = key < km ? key : km;
            }
#pragma unroll
            for (int m = 1; m < 16; m <<= 1) {
                u64 o = __shfl_xor((unsigned long long)km, m);
                km = o < km ? o : km;
            }
            if ((lane & 15) == 0) {
                const int row = row0 + wr * 64 + rt * 16 + (lane >> 4) * 4 + reg;
                atomicMin((unsigned long long*)&keys[row], (unsigned long long)km);
            }
        }
    }
}

// ---- histogram from keys ----
__global__ void k_hist(const u64* __restrict__ keys, int* __restrict__ counts) {
    const int b = blockIdx.x * blockDim.x + threadIdx.x;
    atomicAdd(&counts[(uint)(keys[b] & 0xffffffffull)], 1);
}

// ---- scan of counts -> offsets; EMA cluster sizes -> cs ----
__global__ void k_scan(const int* __restrict__ counts,
                       const float* __restrict__ cluster_size,
                       int* __restrict__ offsets, float* __restrict__ cs) {
    __shared__ int sa[K];
    __shared__ int sb[K];
    __shared__ float sf[K];
    const int t = threadIdx.x;
    const int c = counts[t];

    sa[t] = c;
    __syncthreads();
    int* src = sa;
    int* dst = sb;
    for (int d = 1; d < K; d <<= 1) {
        dst[t] = src[t] + ((t >= d) ? src[t - d] : 0);
        __syncthreads();
        int* tmp = src; src = dst; dst = tmp;
    }
    offsets[t] = src[t] - c;

    float ncs = GAMMA * cluster_size[t] + (1.0f - GAMMA) * ((c == 0) ? 1.0f : (float)c);
    sf[t] = ncs;
    __syncthreads();
    for (int d = K / 2; d > 0; d >>= 1) {
        if (t < d) sf[t] += sf[t + d];
        __syncthreads();
    }
    float n = sf[0];
    cs[t] = (ncs + EPS) / (n + (float)K * EPS) * n;
}

// ---- counting-sort scatter ----
__global__ void k_scatter(const u64* __restrict__ keys, const int* __restrict__ offsets,
                          int* __restrict__ cursor, int* __restrict__ sorted) {
    const int b = blockIdx.x * blockDim.x + threadIdx.x;
    const int k = (int)(uint)(keys[b] & 0xffffffffull);
    const int pos = atomicAdd(&cursor[k], 1);
    sorted[offsets[k] + pos] = b;
}

// ---- per-cluster gather-sum + EMA + normalize -> out ----
__launch_bounds__(512)
__global__ void k_final(const float* __restrict__ x, const int* __restrict__ sorted,
                        const int* __restrict__ offsets, const int* __restrict__ counts,
                        const float* __restrict__ embed_avg, const float* __restrict__ cs,
                        float* __restrict__ out) {
    __shared__ int idx[2048];
    const int k = blockIdx.x;
    const int t = threadIdx.x;   // v index
    const int off = offsets[k];
    const int cnt = counts[k];

    float a0 = 0.f, a1 = 0.f, a2 = 0.f, a3 = 0.f;
    for (int base = 0; base < cnt; base += 2048) {
        int m = min(2048, cnt - base);
        for (int i = t; i < m; i += 512) idx[i] = sorted[off + base + i];
        __syncthreads();
        int i = 0;
        for (; i + 4 <= m; i += 4) {
            long i0 = idx[i + 0], i1 = idx[i + 1], i2 = idx[i + 2], i3 = idx[i + 3];
            a0 += x[i0 * VEC + t];
            a1 += x[i1 * VEC + t];
            a2 += x[i2 * VEC + t];
            a3 += x[i3 * VEC + t];
        }
        for (; i < m; ++i) {
            long i0 = idx[i];
            a0 += x[i0 * VEC + t];
        }
        __syncthreads();
    }
    float es = (a0 + a1) + (a2 + a3);
    float val = (GAMMA * embed_avg[(size_t)t * K + k] + (1.0f - GAMMA) * es) / cs[k];
    out[(size_t)t * K + k] = val;
}

extern "C" void kernel_launch(void* const* d_in, const int* in_sizes, int n_in,
                              void* d_out, int out_size, void* d_ws, size_t ws_size,
                              hipStream_t stream) {
    const float* x            = (const float*)d_in[0];   // (BATCH, VEC)
    const float* w            = (const float*)d_in[1];   // (VEC, K)
    const float* cluster_size = (const float*)d_in[2];   // (K,)
    const float* embed_avg    = (const float*)d_in[3];   // (VEC, K)
    float* out = (float*)d_out;                          // (VEC, K)

    // ws layout: keys | w2 | cs | counts | cursor | offsets | sorted  (~807 KB)
    u64*   keys    = (u64*)d_ws;
    float* w2      = (float*)(keys + BATCH);
    float* cs      = w2 + K;
    int*   counts  = (int*)(cs + K);
    int*   cursor  = counts + K;
    int*   offsets = cursor + K;
    int*   sorted  = offsets + K;

    hipMemsetAsync(keys, 0xFF, (size_t)BATCH * sizeof(u64), stream);
    hipMemsetAsync(counts, 0, 2 * K * sizeof(int), stream);   // counts + cursor

    k_w2<<<K / 16, 256, 0, stream>>>(w, w2);
    k_gemm_argmin<<<(BATCH / BM) * (K / BN), 256, 0, stream>>>(x, w, w2, keys);
    k_hist<<<BATCH / 256, 256, 0, stream>>>(keys, counts);
    k_scan<<<1, K, 0, stream>>>(counts, cluster_size, offsets, cs);
    k_scatter<<<BATCH / 256, 256, 0, stream>>>(keys, offsets, cursor, sorted);
    k_final<<<K, 512, 0, stream>>>(x, sorted, offsets, counts, embed_avg, cs, out);
}

// Round 3
// 487.283 us; speedup vs baseline: 5.9191x; 2.4994x over previous
//
#include <hip/hip_runtime.h>

typedef unsigned int uint;
typedef unsigned short ushort_t;
typedef unsigned long long u64;
typedef __attribute__((ext_vector_type(4))) float f32x4;
typedef __attribute__((ext_vector_type(8))) __bf16 bf16x8;
typedef __attribute__((ext_vector_type(8))) unsigned short us8;

#define BATCH 65536
#define VEC 512
#define K 1024
#define GAMMA 0.99f
#define EPS 1e-05f

#define BM 128
#define BN 128
#define BK 32
#define NK (VEC / BK)   // 16
#define SEG 64          // rows per segment in segmented reduction

// split f32 -> bf16 hi + bf16 lo (truncation; |err| <= 2^-16 |f|)
__device__ __forceinline__ void cvt_hilo(float f, ushort_t& hi, ushort_t& lo) {
    uint b = __float_as_uint(f);
    hi = (ushort_t)(b >> 16);
    float fhi = __uint_as_float(b & 0xffff0000u);
    float flo = f - fhi;                       // exact
    lo = (ushort_t)(__float_as_uint(flo) >> 16);
}

// ---- kernel: column norms of weight (VEC,K) ----
__global__ void k_w2(const float* __restrict__ w, float* __restrict__ w2) {
    __shared__ float red[16][17];
    const int c = blockIdx.x * 16 + (threadIdx.x & 15);
    const int vg = threadIdx.x >> 4;
    float s = 0.f;
    for (int i = 0; i < 32; ++i) {
        float t = w[(size_t)(vg * 32 + i) * K + c];
        s += t * t;
    }
    red[vg][threadIdx.x & 15] = s;
    __syncthreads();
    if (vg == 0) {
        float acc = 0.f;
#pragma unroll
        for (int g = 0; g < 16; ++g) acc += red[g][threadIdx.x & 15];
        w2[c] = acc;
    }
}

// ---- main kernel: split-bf16 MFMA distance GEMM + per-row argmin merge ----
__launch_bounds__(256, 2)
__global__ void k_gemm_argmin(const float* __restrict__ x, const float* __restrict__ w,
                              const float* __restrict__ w2, u64* __restrict__ keys) {
    __shared__ ushort_t a_lds[2][8][2][64][8];   // 32 KB
    __shared__ ushort_t b_lds[2][8][2][64][8];   // 32 KB

    const int blk = blockIdx.x;
    const int gx = blk & 7;
    const int gy = blk >> 3;
    const int row0 = gy * BM;
    const int col0 = gx * BN;
    const int t = threadIdx.x;

    const int a_row = t >> 1;
    const int a_j8 = (t & 1) * 2;
    const int b_col = t & 127;
    const int b_j8 = t >> 7;

    float4 aR[4];
    float  bR[16];

    auto stage_load = [&](int ks) {
        const float* ap = x + (size_t)(row0 + a_row) * VEC + ks * BK + a_j8 * 8;
        aR[0] = *(const float4*)(ap + 0);
        aR[1] = *(const float4*)(ap + 4);
        aR[2] = *(const float4*)(ap + 8);
        aR[3] = *(const float4*)(ap + 12);
        const float* bp = w + (size_t)(ks * BK + b_j8 * 8) * K + col0 + b_col;
#pragma unroll
        for (int j = 0; j < 8; ++j) bR[j] = bp[(size_t)j * K];
        const float* bp2 = bp + (size_t)16 * K;
#pragma unroll
        for (int j = 0; j < 8; ++j) bR[8 + j] = bp2[(size_t)j * K];
    };

    auto stage_write = [&](int buf) {
        const float* af = (const float*)aR;
        const int slab = a_row >> 4;
#pragma unroll
        for (int c = 0; c < 2; ++c) {
            us8 hi, lo;
#pragma unroll
            for (int j = 0; j < 8; ++j) {
                ushort_t h, l; cvt_hilo(af[c * 8 + j], h, l);
                hi[j] = h; lo[j] = l;
            }
            const int lane = (a_row & 15) | ((a_j8 + c) << 4);
            *(us8*)&a_lds[buf][slab][0][lane][0] = hi;
            *(us8*)&a_lds[buf][slab][1][lane][0] = lo;
        }
        const int ct = b_col >> 4;
#pragma unroll
        for (int c = 0; c < 2; ++c) {
            us8 hi, lo;
#pragma unroll
            for (int j = 0; j < 8; ++j) {
                ushort_t h, l; cvt_hilo(bR[c * 8 + j], h, l);
                hi[j] = h; lo[j] = l;
            }
            const int lane = (b_col & 15) | ((b_j8 + 2 * c) << 4);
            *(us8*)&b_lds[buf][ct][0][lane][0] = hi;
            *(us8*)&b_lds[buf][ct][1][lane][0] = lo;
        }
    };

    const int wv = t >> 6;
    const int lane = t & 63;
    const int wr = wv >> 1;
    const int wc = wv & 1;

    f32x4 acc[4][4];
#pragma unroll
    for (int i = 0; i < 4; ++i)
#pragma unroll
        for (int j = 0; j < 4; ++j) acc[i][j] = (f32x4){0.f, 0.f, 0.f, 0.f};

    stage_load(0);
    stage_write(0);
    __syncthreads();

    for (int ks = 0; ks < NK; ++ks) {
        const int buf = ks & 1;
        if (ks + 1 < NK) stage_load(ks + 1);

        bf16x8 ah[4], al[4];
#pragma unroll
        for (int rt = 0; rt < 4; ++rt) {
            ah[rt] = __builtin_bit_cast(bf16x8, *(const us8*)&a_lds[buf][wr * 4 + rt][0][lane][0]);
            al[rt] = __builtin_bit_cast(bf16x8, *(const us8*)&a_lds[buf][wr * 4 + rt][1][lane][0]);
        }
#pragma unroll
        for (int ct = 0; ct < 4; ++ct) {
            bf16x8 bh = __builtin_bit_cast(bf16x8, *(const us8*)&b_lds[buf][wc * 4 + ct][0][lane][0]);
            bf16x8 bl = __builtin_bit_cast(bf16x8, *(const us8*)&b_lds[buf][wc * 4 + ct][1][lane][0]);
#pragma unroll
            for (int rt = 0; rt < 4; ++rt) {
                acc[rt][ct] = __builtin_amdgcn_mfma_f32_16x16x32_bf16(ah[rt], bh, acc[rt][ct], 0, 0, 0);
                acc[rt][ct] = __builtin_amdgcn_mfma_f32_16x16x32_bf16(ah[rt], bl, acc[rt][ct], 0, 0, 0);
                acc[rt][ct] = __builtin_amdgcn_mfma_f32_16x16x32_bf16(al[rt], bh, acc[rt][ct], 0, 0, 0);
            }
        }
        if (ks + 1 < NK) stage_write(buf ^ 1);
        __syncthreads();
    }

    float w2c[4];
#pragma unroll
    for (int ct = 0; ct < 4; ++ct)
        w2c[ct] = w2[col0 + wc * 64 + ct * 16 + (lane & 15)];

#pragma unroll
    for (int rt = 0; rt < 4; ++rt) {
#pragma unroll
        for (int reg = 0; reg < 4; ++reg) {
            u64 km = ~0ull;
#pragma unroll
            for (int ct = 0; ct < 4; ++ct) {
                float dist = w2c[ct] - 2.0f * acc[rt][ct][reg];
                uint su = __float_as_uint(dist);
                su = (su & 0x80000000u) ? ~su : (su | 0x80000000u);
                const int col = col0 + wc * 64 + ct * 16 + (lane & 15);
                u64 key = ((u64)su << 32) | (uint)col;
                km = key < km ? key : km;
            }
#pragma unroll
            for (int m = 1; m < 16; m <<= 1) {
                u64 o = __shfl_xor((unsigned long long)km, m);
                km = o < km ? o : km;
            }
            if ((lane & 15) == 0) {
                const int row = row0 + wr * 64 + rt * 16 + (lane >> 4) * 4 + reg;
                atomicMin((unsigned long long*)&keys[row], (unsigned long long)km);
            }
        }
    }
}

// ---- histogram from keys ----
__global__ void k_hist(const u64* __restrict__ keys, int* __restrict__ counts) {
    const int b = blockIdx.x * blockDim.x + threadIdx.x;
    atomicAdd(&counts[(uint)(keys[b] & 0xffffffffull)], 1);
}

// ---- scan of counts -> offsets; EMA cluster sizes -> cs ----
__global__ void k_scan(const int* __restrict__ counts,
                       const float* __restrict__ cluster_size,
                       int* __restrict__ offsets, float* __restrict__ cs) {
    __shared__ int sa[K];
    __shared__ int sb[K];
    __shared__ float sf[K];
    const int t = threadIdx.x;
    const int c = counts[t];

    sa[t] = c;
    __syncthreads();
    int* src = sa;
    int* dst = sb;
    for (int d = 1; d < K; d <<= 1) {
        dst[t] = src[t] + ((t >= d) ? src[t - d] : 0);
        __syncthreads();
        int* tmp = src; src = dst; dst = tmp;
    }
    offsets[t] = src[t] - c;

    float ncs = GAMMA * cluster_size[t] + (1.0f - GAMMA) * ((c == 0) ? 1.0f : (float)c);
    sf[t] = ncs;
    __syncthreads();
    for (int d = K / 2; d > 0; d >>= 1) {
        if (t < d) sf[t] += sf[t + d];
        __syncthreads();
    }
    float n = sf[0];
    cs[t] = (ncs + EPS) / (n + (float)K * EPS) * n;
}

// ---- counting-sort scatter (also records cluster id per sorted slot) ----
__global__ void k_scatter(const u64* __restrict__ keys, const int* __restrict__ offsets,
                          int* __restrict__ cursor, int* __restrict__ sorted,
                          int* __restrict__ sortedk) {
    const int b = blockIdx.x * blockDim.x + threadIdx.x;
    const int k = (int)(uint)(keys[b] & 0xffffffffull);
    const int pos = atomicAdd(&cursor[k], 1);
    sorted[offsets[k] + pos] = b;
    sortedk[offsets[k] + pos] = k;
}

// ---- balanced segmented reduction: 64 sorted rows per block ----
// esum layout (K, VEC): flushes are coalesced 2KB atomicAdd bursts.
__launch_bounds__(512)
__global__ void k_segred(const float* __restrict__ x, const int* __restrict__ sorted,
                         const int* __restrict__ sortedk, float* __restrict__ esum) {
    __shared__ int srow[SEG];
    __shared__ int skid[SEG];
    const int b = blockIdx.x;
    const int t = threadIdx.x;   // v index
    if (t < SEG) {
        srow[t] = sorted[b * SEG + t];
        skid[t] = sortedk[b * SEG + t];
    }
    __syncthreads();

    float a = 0.f;
    int cur = skid[0];
#pragma unroll 8
    for (int i = 0; i < SEG; ++i) {
        const int k = skid[i];
        if (k != cur) {
            atomicAdd(&esum[(size_t)cur * VEC + t], a);
            a = 0.f;
            cur = k;
        }
        a += x[(size_t)srow[i] * VEC + t];
    }
    atomicAdd(&esum[(size_t)cur * VEC + t], a);
}

// ---- finalize: transpose esum (K,VEC)->(VEC,K), EMA + normalize ----
// grid (K/64, VEC/64), 256 threads; LDS 64x65 tile
__launch_bounds__(256)
__global__ void k_finalize(const float* __restrict__ esum, const float* __restrict__ embed_avg,
                           const float* __restrict__ cs, float* __restrict__ out) {
    __shared__ float tile[64][65];
    const int k0 = blockIdx.x * 64;
    const int v0 = blockIdx.y * 64;
    const int c = threadIdx.x & 63;
    const int r0 = threadIdx.x >> 6;   // 0..3
#pragma unroll
    for (int j = 0; j < 16; ++j) {
        const int r = r0 + j * 4;
        tile[r][c] = esum[(size_t)(k0 + r) * VEC + v0 + c];
    }
    __syncthreads();
    const float csk = cs[k0 + c];
#pragma unroll
    for (int j = 0; j < 16; ++j) {
        const int r = r0 + j * 4;   // v offset
        const size_t o = (size_t)(v0 + r) * K + k0 + c;
        out[o] = (GAMMA * embed_avg[o] + (1.0f - GAMMA) * tile[c][r]) / csk;
    }
}

extern "C" void kernel_launch(void* const* d_in, const int* in_sizes, int n_in,
                              void* d_out, int out_size, void* d_ws, size_t ws_size,
                              hipStream_t stream) {
    const float* x            = (const float*)d_in[0];   // (BATCH, VEC)
    const float* w            = (const float*)d_in[1];   // (VEC, K)
    const float* cluster_size = (const float*)d_in[2];   // (K,)
    const float* embed_avg    = (const float*)d_in[3];   // (VEC, K)
    float* out = (float*)d_out;                          // (VEC, K)

    // ws layout: keys | w2 | cs | counts | cursor | offsets | sorted | sortedk | esum
    u64*   keys    = (u64*)d_ws;
    float* w2      = (float*)(keys + BATCH);
    float* cs      = w2 + K;
    int*   counts  = (int*)(cs + K);
    int*   cursor  = counts + K;
    int*   offsets = cursor + K;
    int*   sorted  = offsets + K;
    int*   sortedk = sorted + BATCH;
    float* esum    = (float*)(sortedk + BATCH);          // (K, VEC), 2 MB

    hipMemsetAsync(keys, 0xFF, (size_t)BATCH * sizeof(u64), stream);
    hipMemsetAsync(counts, 0, 2 * K * sizeof(int), stream);          // counts + cursor
    hipMemsetAsync(esum, 0, (size_t)K * VEC * sizeof(float), stream);

    k_w2<<<K / 16, 256, 0, stream>>>(w, w2);
    k_gemm_argmin<<<(BATCH / BM) * (K / BN), 256, 0, stream>>>(x, w, w2, keys);
    k_hist<<<BATCH / 256, 256, 0, stream>>>(keys, counts);
    k_scan<<<1, K, 0, stream>>>(counts, cluster_size, offsets, cs);
    k_scatter<<<BATCH / 256, 256, 0, stream>>>(keys, offsets, cursor, sorted, sortedk);
    k_segred<<<BATCH / SEG, 512, 0, stream>>>(x, sorted, sortedk, esum);
    k_finalize<<<dim3(K / 64, VEC / 64), 256, 0, stream>>>(esum, embed_avg, cs, out);
}